// Round 4
// baseline (553.902 us; speedup 1.0000x reference)
//
#include <hip/hip_runtime.h>

// SimpleRNN fused kernel for MI355X (gfx950).
// B=256, T=512, I=64, H=256, O=1, fp32.
//
// Decomposition: 256 blocks (one per batch row) x 512 threads.
// Lane (j = tid>>1, half = tid&1) owns W_hh[j][half*128 .. +127] (128 regs)
// and W_ih[j][half*32 .. +31] (32 regs). h is broadcast via LDS
// (double-buffered, one barrier per step). No cross-block communication.
//
// R1: padded LDS half-split (conflicts 1.34e8 -> 0, 608 -> 461 us).
// R2: 4-way k-split / 1024 thr REGRESSED (not wave-latency-bound).
// R3: __launch_bounds__(512,1) alone: VGPR_Count stuck at 104, no change.
// R4: root cause: WRITE_SIZE=8KB proves no scratch spill, yet 104 VGPRs
//     can't hold the 160 declared weight floats => the register allocator
//     REMATERIALIZES the loop-invariant weight loads inside the t-loop
//     (legal for invariant __restrict__ memory). Each step re-issues 40
//     global_load_dwordx4 per thread, each touching 64 distinct cache
//     lines (lanes are 1KB apart) => ~1500-2500 cyc/step of VMEM
//     serialization, matching the gap to the ~740cyc VALU floor.
//     Fix: pass every weight through an empty `asm volatile("+v")` once
//     before the loop. Volatile asm cannot be rematerialized, so the
//     values must stay VGPR-resident. Verification: VGPR_Count >= ~200,
//     WRITE_SIZE stays tiny (no spill fallback).

#define RNN_B 256
#define RNN_T 512
#define RNN_I 64
#define RNN_H 256

// padded layouts: h[0..127] at [0..127], h[128..255] at [132..259]
//                 x[0..31]  at [0..31],  x[32..63]   at [36..67]
#define HSTRIDE 132   // float offset of half-1 h data
#define XSTRIDE 36    // float offset of half-1 x data

__global__ __launch_bounds__(512, 1)
void rnn_fused_kernel(const float* __restrict__ x,     // [B,T,I]
                      const float* __restrict__ W_ih,  // [H,I]
                      const float* __restrict__ W_hh,  // [H,H]
                      const float* __restrict__ b_ih,  // [H]
                      const float* __restrict__ b_hh,  // [H]
                      const float* __restrict__ fc_W,  // [O,H], O=1
                      const float* __restrict__ fc_b,  // [O]
                      float* __restrict__ out)         // [B,O]
{
    const int b    = blockIdx.x;
    const int tid  = threadIdx.x;   // 0..511
    const int j    = tid >> 1;      // output hidden index 0..255
    const int half = tid & 1;       // which half of the k-reduction

    __shared__ float hbuf[2][260];     // double-buffered hidden state (padded)
    __shared__ float xbuf[2][68];      // double-buffered x_t (padded)
    __shared__ float red[8];           // final block reduction

    // padded write index for h[j]
    const int jofs = j + ((j >> 7) << 2);          // j<128 -> j, else j+4
    // padded float4 write index for x staging (valid for tid<16)
    const int xofs = (tid << 2) + (((tid >> 3) & 1) << 2);

    // ---- register-resident weights (scalarized for clean pinning) ----
    float wh[128];  // W_hh[j][half*128 + k]
    float wi[32];   // W_ih[j][half*32  + k]
    {
        const float4* src = reinterpret_cast<const float4*>(W_hh + j * RNN_H + half * 128);
        #pragma unroll
        for (int c = 0; c < 32; ++c) {
            const float4 v = src[c];
            wh[4*c+0] = v.x; wh[4*c+1] = v.y; wh[4*c+2] = v.z; wh[4*c+3] = v.w;
        }
        const float4* s2 = reinterpret_cast<const float4*>(W_ih + j * RNN_I + half * 32);
        #pragma unroll
        for (int c = 0; c < 8; ++c) {
            const float4 v = s2[c];
            wi[4*c+0] = v.x; wi[4*c+1] = v.y; wi[4*c+2] = v.z; wi[4*c+3] = v.w;
        }
    }
    // Pin: values now originate from volatile asm -> cannot be rematerialized
    // (re-loaded) inside the t-loop; allocator must keep them in VGPRs.
    #pragma unroll
    for (int k = 0; k < 128; k += 4)
        asm volatile("" : "+v"(wh[k]), "+v"(wh[k+1]), "+v"(wh[k+2]), "+v"(wh[k+3]));
    #pragma unroll
    for (int k = 0; k < 32; k += 4)
        asm volatile("" : "+v"(wi[k]), "+v"(wi[k+1]), "+v"(wi[k+2]), "+v"(wi[k+3]));

    const float bias2 = b_ih[j] + b_hh[j];
    const float fcw   = fc_W[j];

    // ---- prologue: h0 = 0, stage x[b,0,:] ----
    if (half == 0) hbuf[0][jofs] = 0.0f;
    if (tid < 16) {
        const float4* xs = reinterpret_cast<const float4*>(x + (size_t)b * RNN_T * RNN_I);
        *reinterpret_cast<float4*>(&xbuf[0][xofs]) = xs[tid];
    }
    __syncthreads();

    float hj = 0.0f;  // this lane's h_new[j] (identical in lane pairs)

#define RNN_STEP(CUR, NXT, TT)                                                   \
    {                                                                            \
        float4 xpre;                                                             \
        const bool doPre = (tid < 16) && ((TT) + 1 < RNN_T);                     \
        if (doPre) {                                                             \
            xpre = reinterpret_cast<const float4*>(                              \
                       x + ((size_t)b * RNN_T + ((TT) + 1)) * RNN_I)[tid];       \
        }                                                                        \
        float a0 = 0.f, a1 = 0.f, a2 = 0.f, a3 = 0.f;                            \
        const float4* hs = reinterpret_cast<const float4*>(&hbuf[CUR][half * HSTRIDE]); \
        _Pragma("unroll")                                                        \
        for (int c = 0; c < 32; ++c) {                                           \
            const float4 h4 = hs[c];   /* broadcast; halves on disjoint banks */ \
            a0 = fmaf(h4.x, wh[4*c+0], a0);                                      \
            a1 = fmaf(h4.y, wh[4*c+1], a1);                                      \
            a2 = fmaf(h4.z, wh[4*c+2], a2);                                      \
            a3 = fmaf(h4.w, wh[4*c+3], a3);                                      \
        }                                                                        \
        const float4* xs4 = reinterpret_cast<const float4*>(&xbuf[CUR][half * XSTRIDE]); \
        _Pragma("unroll")                                                        \
        for (int c = 0; c < 8; ++c) {                                            \
            const float4 x4 = xs4[c];                                            \
            a0 = fmaf(x4.x, wi[4*c+0], a0);                                      \
            a1 = fmaf(x4.y, wi[4*c+1], a1);                                      \
            a2 = fmaf(x4.z, wi[4*c+2], a2);                                      \
            a3 = fmaf(x4.w, wi[4*c+3], a3);                                      \
        }                                                                        \
        float partial = (a0 + a1) + (a2 + a3);                                   \
        partial += __shfl_xor(partial, 1, 64);   /* add partner half's partial */\
        const float z  = partial + bias2;                                        \
        const float zc = fminf(fmaxf(z, -10.f), 10.f);                           \
        const float e  = exp2f(zc * 2.8853900817779268f);     /* e^(2z) */       \
        const float hn = (e - 1.f) * __builtin_amdgcn_rcpf(e + 1.f);             \
        hj = hn;                                                                 \
        if (half == 0) hbuf[NXT][jofs] = hn;                                     \
        if (doPre) *reinterpret_cast<float4*>(&xbuf[NXT][xofs]) = xpre;          \
        __syncthreads();                                                         \
    }

    // t-loop unrolled x2: removes the per-step buffer-select on hbuf/xbuf
    for (int t = 0; t < RNN_T; t += 2) {
        RNN_STEP(0, 1, t)
        RNN_STEP(1, 0, t + 1)
    }
#undef RNN_STEP

    // ---- epilogue: out[b] = sum_j h_T[j]*fc_W[j] + fc_b ----
    float term = (half == 0) ? hj * fcw : 0.0f;
    #pragma unroll
    for (int s = 1; s < 64; s <<= 1) term += __shfl_xor(term, s, 64);
    const int wid = tid >> 6;
    if ((tid & 63) == 0) red[wid] = term;
    __syncthreads();
    if (tid == 0) {
        float s = 0.f;
        #pragma unroll
        for (int w = 0; w < 8; ++w) s += red[w];
        out[b] = s + fc_b[0];
    }
}

extern "C" void kernel_launch(void* const* d_in, const int* in_sizes, int n_in,
                              void* d_out, int out_size, void* d_ws, size_t ws_size,
                              hipStream_t stream) {
    const float* x    = (const float*)d_in[0];
    const float* W_ih = (const float*)d_in[1];
    const float* W_hh = (const float*)d_in[2];
    const float* b_ih = (const float*)d_in[3];
    const float* b_hh = (const float*)d_in[4];
    const float* fc_W = (const float*)d_in[5];
    const float* fc_b = (const float*)d_in[6];
    float* out = (float*)d_out;

    rnn_fused_kernel<<<RNN_B, 512, 0, stream>>>(x, W_ih, W_hh, b_ih, b_hh, fc_W, fc_b, out);
}

// Round 5
// 451.287 us; speedup vs baseline: 1.2274x; 1.2274x over previous
//
#include <hip/hip_runtime.h>

// SimpleRNN fused kernel for MI355X (gfx950).
// B=256, T=512, I=64, H=256, O=1, fp32.
//
// Decomposition: 256 blocks (one per batch row) x 512 threads.
// Lane (j = tid>>1, half = tid&1) owns W_hh[j][half*128 .. +127] (128 regs)
// and W_ih[j][half*32 .. +31] (32 regs). h is broadcast via LDS
// (double-buffered, one barrier per step). No cross-block communication.
//
// R1: padded LDS half-split (conflicts 1.34e8 -> 0, 608 -> 461 us).
// R2: 4-way k-split / 1024 thr REGRESSED (not wave-latency-bound).
// R3: __launch_bounds__(512,1): VGPR stuck at 104 -- only sets a floor
//     (min waves/EU), allocator's occupancy heuristic still minimizes
//     pressure and rematerializes the weight loads inside the t-loop.
// R4: asm-volatile pin: allocator stashed weights in AGPRs instead
//     (VGPR=100, no scratch writes, +accvgpr_read churn) -- regressed.
// R5: the correct knob: amdgpu_waves_per_eu(2,2). Capping MAX waves/EU
//     at 2 (which a 512-thread/1-block-CU config already implies) tells
//     RA that holding 160 weight floats in arch VGPRs costs zero
//     occupancy -> no remat, no AGPR stash. Verification: VGPR >= ~200.

#define RNN_B 256
#define RNN_T 512
#define RNN_I 64
#define RNN_H 256

// padded layouts: h[0..127] at [0..127], h[128..255] at [132..259]
//                 x[0..31]  at [0..31],  x[32..63]   at [36..67]
#define HSTRIDE 132   // float offset of half-1 h data
#define XSTRIDE 36    // float offset of half-1 x data

__global__
__attribute__((amdgpu_flat_work_group_size(512, 512), amdgpu_waves_per_eu(2, 2)))
void rnn_fused_kernel(const float* __restrict__ x,     // [B,T,I]
                      const float* __restrict__ W_ih,  // [H,I]
                      const float* __restrict__ W_hh,  // [H,H]
                      const float* __restrict__ b_ih,  // [H]
                      const float* __restrict__ b_hh,  // [H]
                      const float* __restrict__ fc_W,  // [O,H], O=1
                      const float* __restrict__ fc_b,  // [O]
                      float* __restrict__ out)         // [B,O]
{
    const int b    = blockIdx.x;
    const int tid  = threadIdx.x;   // 0..511
    const int j    = tid >> 1;      // output hidden index 0..255
    const int half = tid & 1;       // which half of the k-reduction

    __shared__ float hbuf[2][260];     // double-buffered hidden state (padded)
    __shared__ float xbuf[2][68];      // double-buffered x_t (padded)
    __shared__ float red[8];           // final block reduction

    // padded write index for h[j]
    const int jofs = j + ((j >> 7) << 2);          // j<128 -> j, else j+4
    // padded float4 write index for x staging (valid for tid<16)
    const int xofs = (tid << 2) + (((tid >> 3) & 1) << 2);

    // ---- register-resident weights (160 floats; waves_per_eu(2,2) budget) ----
    float4 wh[32];  // W_hh[j][half*128 + 4c + {0..3}]
    float4 wi[8];   // W_ih[j][half*32  + 4c + {0..3}]
    {
        const float4* src = reinterpret_cast<const float4*>(W_hh + j * RNN_H + half * 128);
        #pragma unroll
        for (int c = 0; c < 32; ++c) wh[c] = src[c];
        const float4* s2 = reinterpret_cast<const float4*>(W_ih + j * RNN_I + half * 32);
        #pragma unroll
        for (int c = 0; c < 8; ++c) wi[c] = s2[c];
    }
    const float bias2 = b_ih[j] + b_hh[j];
    const float fcw   = fc_W[j];

    // ---- prologue: h0 = 0, stage x[b,0,:] ----
    if (half == 0) hbuf[0][jofs] = 0.0f;
    if (tid < 16) {
        const float4* xs = reinterpret_cast<const float4*>(x + (size_t)b * RNN_T * RNN_I);
        *reinterpret_cast<float4*>(&xbuf[0][xofs]) = xs[tid];
    }
    __syncthreads();

    float hj = 0.0f;  // this lane's h_new[j] (identical in lane pairs)

#define RNN_STEP(CUR, NXT, TT)                                                   \
    {                                                                            \
        float4 xpre;                                                             \
        const bool doPre = (tid < 16) && ((TT) + 1 < RNN_T);                     \
        if (doPre) {                                                             \
            xpre = reinterpret_cast<const float4*>(                              \
                       x + ((size_t)b * RNN_T + ((TT) + 1)) * RNN_I)[tid];       \
        }                                                                        \
        float a0 = 0.f, a1 = 0.f, a2 = 0.f, a3 = 0.f;                            \
        const float4* hs = reinterpret_cast<const float4*>(&hbuf[CUR][half * HSTRIDE]); \
        _Pragma("unroll")                                                        \
        for (int c = 0; c < 32; ++c) {                                           \
            const float4 h4 = hs[c];   /* broadcast; halves on disjoint banks */ \
            a0 = fmaf(h4.x, wh[c].x, a0);                                        \
            a1 = fmaf(h4.y, wh[c].y, a1);                                        \
            a2 = fmaf(h4.z, wh[c].z, a2);                                        \
            a3 = fmaf(h4.w, wh[c].w, a3);                                        \
        }                                                                        \
        const float4* xs4 = reinterpret_cast<const float4*>(&xbuf[CUR][half * XSTRIDE]); \
        _Pragma("unroll")                                                        \
        for (int c = 0; c < 8; ++c) {                                            \
            const float4 x4 = xs4[c];                                            \
            a0 = fmaf(x4.x, wi[c].x, a0);                                        \
            a1 = fmaf(x4.y, wi[c].y, a1);                                        \
            a2 = fmaf(x4.z, wi[c].z, a2);                                        \
            a3 = fmaf(x4.w, wi[c].w, a3);                                        \
        }                                                                        \
        float partial = (a0 + a1) + (a2 + a3);                                   \
        partial += __shfl_xor(partial, 1, 64);   /* add partner half's partial */\
        const float z  = partial + bias2;                                        \
        const float zc = fminf(fmaxf(z, -10.f), 10.f);                           \
        const float e  = exp2f(zc * 2.8853900817779268f);     /* e^(2z) */       \
        const float hn = (e - 1.f) * __builtin_amdgcn_rcpf(e + 1.f);             \
        hj = hn;                                                                 \
        if (half == 0) hbuf[NXT][jofs] = hn;                                     \
        if (doPre) *reinterpret_cast<float4*>(&xbuf[NXT][xofs]) = xpre;          \
        __syncthreads();                                                         \
    }

    // t-loop unrolled x2: removes the per-step buffer-select on hbuf/xbuf
    for (int t = 0; t < RNN_T; t += 2) {
        RNN_STEP(0, 1, t)
        RNN_STEP(1, 0, t + 1)
    }
#undef RNN_STEP

    // ---- epilogue: out[b] = sum_j h_T[j]*fc_W[j] + fc_b ----
    float term = (half == 0) ? hj * fcw : 0.0f;
    #pragma unroll
    for (int s = 1; s < 64; s <<= 1) term += __shfl_xor(term, s, 64);
    const int wid = tid >> 6;
    if ((tid & 63) == 0) red[wid] = term;
    __syncthreads();
    if (tid == 0) {
        float s = 0.f;
        #pragma unroll
        for (int w = 0; w < 8; ++w) s += red[w];
        out[b] = s + fc_b[0];
    }
}

extern "C" void kernel_launch(void* const* d_in, const int* in_sizes, int n_in,
                              void* d_out, int out_size, void* d_ws, size_t ws_size,
                              hipStream_t stream) {
    const float* x    = (const float*)d_in[0];
    const float* W_ih = (const float*)d_in[1];
    const float* W_hh = (const float*)d_in[2];
    const float* b_ih = (const float*)d_in[3];
    const float* b_hh = (const float*)d_in[4];
    const float* fc_W = (const float*)d_in[5];
    const float* fc_b = (const float*)d_in[6];
    float* out = (float*)d_out;

    rnn_fused_kernel<<<RNN_B, 512, 0, stream>>>(x, W_ih, W_hh, b_ih, b_hh, fc_W, fc_b, out);
}